// Round 1
// baseline (430.544 us; speedup 1.0000x reference)
//
#include <hip/hip_runtime.h>
#include <stdint.h>
#include <math.h>

using bf16x8 = __attribute__((ext_vector_type(8))) short;
using bf16x4 = __attribute__((ext_vector_type(4))) short;
using f32x4  = __attribute__((ext_vector_type(4))) float;

#define DEV static __device__ __forceinline__

DEV float bf2f(short s) {
  union { unsigned u; float f; } v; v.u = ((unsigned)(unsigned short)s) << 16; return v.f;
}
DEV short f2bf(float f) {
  union { float ff; unsigned u; } v; v.ff = f;
  unsigned r = v.u + 0x7fffu + ((v.u >> 16) & 1u);
  return (short)(r >> 16);
}

DEV f32x4 mfma16x16x32(bf16x8 a, bf16x8 b, f32x4 c) {
  return __builtin_amdgcn_mfma_f32_16x16x32_bf16(a, b, c, 0, 0, 0);
}

DEV void glds16(const void* g, void* l) {
  __builtin_amdgcn_global_load_lds(
      (__attribute__((address_space(1))) void*)(uintptr_t)(g),
      (__attribute__((address_space(3))) void*)(l), 16, 0, 0);
}

#define B_   2
#define N_   2048
#define DIM_ 1024
#define H_   16
#define DH_  64
#define BH_  (B_ * H_)
#define BN_  (B_ * N_)

// ---------------------------------------------------------------------------
// 1) cos/sin table: cs[(n*32+j)*2] = cos(n * 10000^(-2j/64)), +1 = sin
// ---------------------------------------------------------------------------
__global__ void cs_kernel(float* __restrict__ cs) {
  int tid = blockIdx.x * blockDim.x + threadIdx.x;   // 65536 = 2048 * 32
  int n = tid >> 5, j = tid & 31;
  float inv = powf(10000.0f, -(float)(2 * j) / 64.0f);
  float ang = (float)n * inv;
  cs[2 * tid]     = cosf(ang);
  cs[2 * tid + 1] = sinf(ang);
}

// ---------------------------------------------------------------------------
// 2) fp32 -> bf16 elementwise (for x)
// ---------------------------------------------------------------------------
__global__ __launch_bounds__(256) void conv_kernel(const float* __restrict__ src,
                                                   short* __restrict__ dst) {
  int i = (blockIdx.x * 256 + threadIdx.x) * 8;
  float4 a = *(const float4*)(src + i);
  float4 b = *(const float4*)(src + i + 4);
  bf16x8 o;
  o[0] = f2bf(a.x); o[1] = f2bf(a.y); o[2] = f2bf(a.z); o[3] = f2bf(a.w);
  o[4] = f2bf(b.x); o[5] = f2bf(b.y); o[6] = f2bf(b.z); o[7] = f2bf(b.w);
  *(bf16x8*)(dst + i) = o;
}

// ---------------------------------------------------------------------------
// 3) transpose fp32 [R][C] -> bf16 [C][R]  (64x64 LDS tiles)
// ---------------------------------------------------------------------------
__global__ __launch_bounds__(256) void transw_kernel(const float* __restrict__ src,
                                                     short* __restrict__ dst,
                                                     int R, int C) {
  __shared__ unsigned short lds[64 * 65];
  const int t = threadIdx.x;
  const int cb = blockIdx.x * 64, rb = blockIdx.y * 64;
  #pragma unroll
  for (int pass = 0; pass < 4; ++pass) {
    int r  = pass * 16 + (t >> 4);
    int cc = (t & 15) * 4;
    float4 v = *(const float4*)(src + (size_t)(rb + r) * C + cb + cc);
    lds[(cc + 0) * 65 + r] = (unsigned short)f2bf(v.x);
    lds[(cc + 1) * 65 + r] = (unsigned short)f2bf(v.y);
    lds[(cc + 2) * 65 + r] = (unsigned short)f2bf(v.z);
    lds[(cc + 3) * 65 + r] = (unsigned short)f2bf(v.w);
  }
  __syncthreads();
  const int cl = t >> 2, chunk = t & 3;
  bf16x8 o0, o1;
  #pragma unroll
  for (int j = 0; j < 8; ++j) {
    o0[j] = (short)lds[cl * 65 + chunk * 16 + j];
    o1[j] = (short)lds[cl * 65 + chunk * 16 + 8 + j];
  }
  size_t off = (size_t)(cb + cl) * R + rb + chunk * 16;
  *(bf16x8*)(dst + off)     = o0;
  *(bf16x8*)(dst + off + 8) = o1;
}

// ---------------------------------------------------------------------------
// 4) GEMM: C[M][N] = A[M][K] (bf16, row-major) @ BT[N][K]^T (bf16)
//    m97-style: 128x128 tile, BK=32, 4 waves (2x2 of 64x64), global_load_lds.
// ---------------------------------------------------------------------------
template <bool OUTBF16>
__global__ __launch_bounds__(256) void gemm_bt_kernel(const short* __restrict__ A,
                                                      const short* __restrict__ BT,
                                                      void* __restrict__ Cout,
                                                      int M, int N, int K) {
  __shared__ short As[128 * 32];
  __shared__ short Bs[128 * 32];
  const int t = threadIdx.x;
  const int lane = t & 63, w = t >> 6;
  const int c = lane & 15, g = lane >> 4;
  const int wm = w >> 1, wn = w & 1;
  const int mbase = blockIdx.y * 128, nbase = blockIdx.x * 128;
  const short* Ab = A + (size_t)mbase * K;
  const short* Bb = BT + (size_t)nbase * K;
  const int sr  = t >> 2;        // staging row 0..63
  const int sc2 = (t & 3) * 8;   // staging col chunk (8 bf16 = 16 B)
  f32x4 acc[4][4] = {};
  for (int kb2 = 0; kb2 < K; kb2 += 32) {
    glds16(Ab + (size_t)sr * K + kb2 + sc2,        As + t * 8);
    glds16(Ab + (size_t)(sr + 64) * K + kb2 + sc2, As + 2048 + t * 8);
    glds16(Bb + (size_t)sr * K + kb2 + sc2,        Bs + t * 8);
    glds16(Bb + (size_t)(sr + 64) * K + kb2 + sc2, Bs + 2048 + t * 8);
    __syncthreads();
    bf16x8 af[4], bfr[4];
    #pragma unroll
    for (int mi = 0; mi < 4; ++mi)
      af[mi] = *(const bf16x8*)&As[(wm * 64 + mi * 16 + c) * 32 + g * 8];
    #pragma unroll
    for (int ni = 0; ni < 4; ++ni)
      bfr[ni] = *(const bf16x8*)&Bs[(wn * 64 + ni * 16 + c) * 32 + g * 8];
    #pragma unroll
    for (int mi = 0; mi < 4; ++mi)
      #pragma unroll
      for (int ni = 0; ni < 4; ++ni)
        acc[mi][ni] = mfma16x16x32(af[mi], bfr[ni], acc[mi][ni]);
    __syncthreads();
  }
  #pragma unroll
  for (int mi = 0; mi < 4; ++mi) {
    const int row = mbase + wm * 64 + mi * 16 + g * 4;
    #pragma unroll
    for (int ni = 0; ni < 4; ++ni) {
      const int col = nbase + wn * 64 + ni * 16 + c;
      #pragma unroll
      for (int r = 0; r < 4; ++r) {
        if constexpr (OUTBF16)
          ((short*)Cout)[(size_t)(row + r) * N + col] = f2bf(acc[mi][ni][r]);
        else
          ((float*)Cout)[(size_t)(row + r) * N + col] = acc[mi][ni][r];
      }
    }
  }
}

// ---------------------------------------------------------------------------
// 5) RoPE on q,k: qkv bf16 [4096][3072] cols 0..2047 -> qb/kb [BH][N][64] bf16
//    q additionally scaled by 0.125 (exact pow2, folds softmax scale)
// ---------------------------------------------------------------------------
__global__ __launch_bounds__(256) void ropeqk_kernel(const short* __restrict__ qkv,
                                                     const float* __restrict__ cs,
                                                     short* __restrict__ qb,
                                                     short* __restrict__ kb) {
  int tid = blockIdx.x * 256 + threadIdx.x;  // 2097152 threads, 4 elems each
  int e   = tid * 4;
  int bn  = e >> 11;
  int col = e & 2047;
  int i3  = col >> 10;
  int h   = (col >> 6) & 15;
  int d   = col & 63;
  int n   = bn & (N_ - 1);
  int b   = bn >> 11;
  bf16x4 v = *(const bf16x4*)(qkv + (size_t)bn * 3072 + col);
  float4 t4 = *(const float4*)(cs + ((size_t)n * 32 + (d >> 1)) * 2); // c0,s0,c1,s1
  float x0 = bf2f(v[0]), x1 = bf2f(v[1]), x2 = bf2f(v[2]), x3 = bf2f(v[3]);
  float r0 = x0 * t4.x - x1 * t4.y;
  float r1 = x0 * t4.y + x1 * t4.x;
  float r2 = x2 * t4.z - x3 * t4.w;
  float r3 = x2 * t4.w + x3 * t4.z;
  float sc = (i3 == 0) ? 0.125f : 1.0f;
  bf16x4 ov;
  ov[0] = f2bf(r0 * sc); ov[1] = f2bf(r1 * sc);
  ov[2] = f2bf(r2 * sc); ov[3] = f2bf(r3 * sc);
  short* dst = (i3 == 0) ? qb : kb;
  *(bf16x4*)(dst + (((size_t)(b * H_ + h) * N_ + n) * DH_ + d)) = ov;
}

// ---------------------------------------------------------------------------
// 6) V transpose: qkv cols 2048..3071 -> vT [BH][64][N] bf16
// ---------------------------------------------------------------------------
__global__ __launch_bounds__(256) void transv_kernel(const short* __restrict__ qkv,
                                                     short* __restrict__ vT) {
  __shared__ unsigned short lds[64 * 65];
  const int t = threadIdx.x;
  const int ntile = blockIdx.x;  // 0..31
  const int bh = blockIdx.y;     // 0..31
  const int b = bh >> 4, h = bh & 15;
  #pragma unroll
  for (int pass = 0; pass < 2; ++pass) {
    int rloc = pass * 32 + (t >> 3);
    int dc = t & 7;
    const short* src = qkv + (size_t)(b * N_ + ntile * 64 + rloc) * 3072 + 2048 + h * 64 + dc * 8;
    bf16x8 v = *(const bf16x8*)src;
    #pragma unroll
    for (int j = 0; j < 8; ++j) lds[(dc * 8 + j) * 65 + rloc] = (unsigned short)v[j];
  }
  __syncthreads();
  const int dl = t >> 2, chunk = t & 3;
  bf16x8 o0, o1;
  #pragma unroll
  for (int j = 0; j < 8; ++j) {
    o0[j] = (short)lds[dl * 65 + chunk * 16 + j];
    o1[j] = (short)lds[dl * 65 + chunk * 16 + 8 + j];
  }
  short* dst = vT + ((size_t)bh * 64 + dl) * N_ + ntile * 64 + chunk * 16;
  *(bf16x8*)dst       = o0;
  *(bf16x8*)(dst + 8) = o1;
}

// ---------------------------------------------------------------------------
// 7) Flash attention. Swapped-QK (S^T = mfma(K,Q)) so each lane owns one
//    q-row (i = lane&15). PV uses a consistent k<->j slot remap so the
//    B-operand is the lane's own p registers (no shuffles, no LDS).
//    Grid (N/64, BH), 4 waves x 16 q-rows. Q pre-scaled by 1/8.
// ---------------------------------------------------------------------------
__global__ __launch_bounds__(256) void attn_kernel(const short* __restrict__ qb,
                                                   const short* __restrict__ kb,
                                                   const short* __restrict__ vT,
                                                   short* __restrict__ attn_out) {
  const int t = threadIdx.x;
  const int lane = t & 63, w = t >> 6;
  const int c = lane & 15, g = lane >> 4;
  const int bh = blockIdx.y;
  const int qrow = blockIdx.x * 64 + w * 16 + c;  // 0..2047
  const short* qp = qb + ((size_t)bh * N_ + qrow) * DH_;
  const bf16x8 qf0 = *(const bf16x8*)(qp + g * 8);
  const bf16x8 qf1 = *(const bf16x8*)(qp + 32 + g * 8);
  const short* kbase = kb + (size_t)bh * N_ * DH_;
  const short* vbase = vT + (size_t)bh * DH_ * N_;
  float M = -INFINITY, L = 0.0f;
  f32x4 o[4] = {};
  for (int kv = 0; kv < N_; kv += 64) {
    f32x4 s[4];
    #pragma unroll
    for (int jt = 0; jt < 4; ++jt) {
      const short* kr = kbase + (size_t)(kv + jt * 16 + c) * DH_;
      f32x4 a = {0.f, 0.f, 0.f, 0.f};
      a = mfma16x16x32(*(const bf16x8*)(kr + g * 8), qf0, a);
      a = mfma16x16x32(*(const bf16x8*)(kr + 32 + g * 8), qf1, a);
      s[jt] = a;  // S^T[kv+jt*16+g*4+r][qrow], lane's q-row = c
    }
    float mx = -INFINITY;
    #pragma unroll
    for (int jt = 0; jt < 4; ++jt)
      #pragma unroll
      for (int r = 0; r < 4; ++r) mx = fmaxf(mx, s[jt][r]);
    mx = fmaxf(mx, __shfl_xor(mx, 16));
    mx = fmaxf(mx, __shfl_xor(mx, 32));
    const float mnew = fmaxf(M, mx);
    const float corr = __expf(M - mnew);  // exp(-inf)=0 on first tile
    float rs = 0.f;
    #pragma unroll
    for (int jt = 0; jt < 4; ++jt)
      #pragma unroll
      for (int r = 0; r < 4; ++r) {
        s[jt][r] = __expf(s[jt][r] - mnew);
        rs += s[jt][r];
      }
    rs += __shfl_xor(rs, 16);
    rs += __shfl_xor(rs, 32);
    L = L * corr + rs;
    M = mnew;
    #pragma unroll
    for (int dt = 0; dt < 4; ++dt) o[dt] *= corr;
    // B-operand for PV: lane's own p values. Slot ii<4 -> j=jt0*16+g*4+ii,
    // slot ii>=4 -> j=(jt0+1)*16+g*4+(ii-4); frag0: jt0=0, frag1: jt0=2.
    bf16x8 pf0, pf1;
    #pragma unroll
    for (int r = 0; r < 4; ++r) {
      pf0[r]     = f2bf(s[0][r]);
      pf0[4 + r] = f2bf(s[1][r]);
      pf1[r]     = f2bf(s[2][r]);
      pf1[4 + r] = f2bf(s[3][r]);
    }
    // A-operand: V^T rows d=dt*16+c, matching j columns per slot map.
    #pragma unroll
    for (int dt = 0; dt < 4; ++dt) {
      const short* vr = vbase + (size_t)(dt * 16 + c) * N_ + kv;
      bf16x4 a0 = *(const bf16x4*)(vr + g * 4);
      bf16x4 a1 = *(const bf16x4*)(vr + 16 + g * 4);
      bf16x4 a2 = *(const bf16x4*)(vr + 32 + g * 4);
      bf16x4 a3 = *(const bf16x4*)(vr + 48 + g * 4);
      o[dt] = mfma16x16x32(__builtin_shufflevector(a0, a1, 0, 1, 2, 3, 4, 5, 6, 7), pf0, o[dt]);
      o[dt] = mfma16x16x32(__builtin_shufflevector(a2, a3, 0, 1, 2, 3, 4, 5, 6, 7), pf1, o[dt]);
    }
  }
  const float inv = 1.0f / L;
  const int b = bh >> 4, h = bh & 15;
  short* op = attn_out + ((size_t)b * N_ + qrow) * (H_ * DH_) + h * DH_;
  #pragma unroll
  for (int dt = 0; dt < 4; ++dt) {
    bf16x4 ov;
    #pragma unroll
    for (int r = 0; r < 4; ++r) ov[r] = f2bf(o[dt][r] * inv);
    *(bf16x4*)(op + dt * 16 + g * 4) = ov;
  }
}

// ---------------------------------------------------------------------------
extern "C" void kernel_launch(void* const* d_in, const int* in_sizes, int n_in,
                              void* d_out, int out_size, void* d_ws, size_t ws_size,
                              hipStream_t stream) {
  const float* x    = (const float*)d_in[0];
  const float* Wqkv = (const float*)d_in[1];
  const float* Wout = (const float*)d_in[2];
  char* ws = (char*)d_ws;
  // workspace layout (MiB offsets)
  short* xb    = (short*)(ws);                        // 8 MiB  [4096][1024]
  short* WqkvT = (short*)(ws + ((size_t)8 << 20));    // 6 MiB  [3072][1024]
  short* WoutT = (short*)(ws + ((size_t)14 << 20));   // 2 MiB  [1024][1024]
  short* qkv   = (short*)(ws + ((size_t)16 << 20));   // 24 MiB [4096][3072]
  short* qb    = (short*)(ws + ((size_t)40 << 20));   // 8 MiB  [32][2048][64]
  short* kb    = (short*)(ws + ((size_t)48 << 20));   // 8 MiB
  short* vT    = (short*)(ws + ((size_t)56 << 20));   // 8 MiB  [32][64][2048]
  short* attn  = (short*)(ws + ((size_t)64 << 20));   // 8 MiB  [4096][1024]
  float* cs    = (float*)(ws + ((size_t)72 << 20));   // 0.5 MiB [2048][32][2]

  cs_kernel<<<dim3(256), 256, 0, stream>>>(cs);
  conv_kernel<<<dim3(2048), 256, 0, stream>>>(x, xb);                       // x -> bf16
  transw_kernel<<<dim3(48, 16), 256, 0, stream>>>(Wqkv, WqkvT, 1024, 3072); // Wqkv^T
  transw_kernel<<<dim3(16, 16), 256, 0, stream>>>(Wout, WoutT, 1024, 1024); // Wout^T
  gemm_bt_kernel<true><<<dim3(24, 32), 256, 0, stream>>>(xb, WqkvT, (void*)qkv, 4096, 3072, 1024);
  ropeqk_kernel<<<dim3(8192), 256, 0, stream>>>(qkv, cs, qb, kb);
  transv_kernel<<<dim3(32, 32), 256, 0, stream>>>(qkv, vT);
  attn_kernel<<<dim3(32, 32), 256, 0, stream>>>(qb, kb, vT, attn);
  gemm_bt_kernel<false><<<dim3(8, 32), 256, 0, stream>>>(attn, WoutT, d_out, 4096, 1024, 1024);
}

// Round 3
// 167.959 us; speedup vs baseline: 2.5634x; 2.5634x over previous
//
#include <hip/hip_runtime.h>
#include <stdint.h>
#include <math.h>

using bf16x8 = __attribute__((ext_vector_type(8))) short;
using bf16x4 = __attribute__((ext_vector_type(4))) short;
using f32x4  = __attribute__((ext_vector_type(4))) float;

#define DEV static __device__ __forceinline__

DEV float bf2f(short s) {
  union { unsigned u; float f; } v; v.u = ((unsigned)(unsigned short)s) << 16; return v.f;
}
DEV short f2bf(float f) {
  union { float ff; unsigned u; } v; v.ff = f;
  unsigned r = v.u + 0x7fffu + ((v.u >> 16) & 1u);
  return (short)(r >> 16);
}

DEV f32x4 mfma16x16x32(bf16x8 a, bf16x8 b, f32x4 c) {
  return __builtin_amdgcn_mfma_f32_16x16x32_bf16(a, b, c, 0, 0, 0);
}

DEV void glds16(const void* g, void* l) {
  __builtin_amdgcn_global_load_lds(
      (__attribute__((address_space(1))) void*)(uintptr_t)(g),
      (__attribute__((address_space(3))) void*)(l), 16, 0, 0);
}

#define B_   2
#define N_   2048
#define DIM_ 1024
#define H_   16
#define DH_  64
#define BH_  (B_ * H_)
#define BN_  (B_ * N_)

// ---------------------------------------------------------------------------
// 1) cos/sin table: cs[(n*32+j)*2] = cos(n * 10000^(-2j/64)), +1 = sin
// ---------------------------------------------------------------------------
__global__ void cs_kernel(float* __restrict__ cs) {
  int tid = blockIdx.x * blockDim.x + threadIdx.x;   // 65536 = 2048 * 32
  int n = tid >> 5, j = tid & 31;
  float inv = powf(10000.0f, -(float)(2 * j) / 64.0f);
  float ang = (float)n * inv;
  cs[2 * tid]     = cosf(ang);
  cs[2 * tid + 1] = sinf(ang);
}

// ---------------------------------------------------------------------------
// 2) fp32 -> bf16 elementwise (for x)
// ---------------------------------------------------------------------------
__global__ __launch_bounds__(256) void conv_kernel(const float* __restrict__ src,
                                                   short* __restrict__ dst) {
  int i = (blockIdx.x * 256 + threadIdx.x) * 8;
  float4 a = *(const float4*)(src + i);
  float4 b = *(const float4*)(src + i + 4);
  bf16x8 o;
  o[0] = f2bf(a.x); o[1] = f2bf(a.y); o[2] = f2bf(a.z); o[3] = f2bf(a.w);
  o[4] = f2bf(b.x); o[5] = f2bf(b.y); o[6] = f2bf(b.z); o[7] = f2bf(b.w);
  *(bf16x8*)(dst + i) = o;
}

// ---------------------------------------------------------------------------
// 3) transpose fp32 [R][C] -> bf16 [C][R]  (64x64 LDS tiles)
// ---------------------------------------------------------------------------
__global__ __launch_bounds__(256) void transw_kernel(const float* __restrict__ src,
                                                     short* __restrict__ dst,
                                                     int R, int C) {
  __shared__ unsigned short lds[64 * 65];
  const int t = threadIdx.x;
  const int cb = blockIdx.x * 64, rb = blockIdx.y * 64;
  #pragma unroll
  for (int pass = 0; pass < 4; ++pass) {
    int r  = pass * 16 + (t >> 4);
    int cc = (t & 15) * 4;
    float4 v = *(const float4*)(src + (size_t)(rb + r) * C + cb + cc);
    lds[(cc + 0) * 65 + r] = (unsigned short)f2bf(v.x);
    lds[(cc + 1) * 65 + r] = (unsigned short)f2bf(v.y);
    lds[(cc + 2) * 65 + r] = (unsigned short)f2bf(v.z);
    lds[(cc + 3) * 65 + r] = (unsigned short)f2bf(v.w);
  }
  __syncthreads();
  const int cl = t >> 2, chunk = t & 3;
  bf16x8 o0, o1;
  #pragma unroll
  for (int j = 0; j < 8; ++j) {
    o0[j] = (short)lds[cl * 65 + chunk * 16 + j];
    o1[j] = (short)lds[cl * 65 + chunk * 16 + 8 + j];
  }
  size_t off = (size_t)(cb + cl) * R + rb + chunk * 16;
  *(bf16x8*)(dst + off)     = o0;
  *(bf16x8*)(dst + off + 8) = o1;
}

// ---------------------------------------------------------------------------
// 4) GEMM: C[M][N] = A[M][K] (bf16, row-major) @ BT[N][K]^T (bf16)
//    m97-style: 128x128 tile, BK=32, 4 waves (2x2 of 64x64), global_load_lds.
// ---------------------------------------------------------------------------
template <bool OUTBF16>
__global__ __launch_bounds__(256) void gemm_bt_kernel(const short* __restrict__ A,
                                                      const short* __restrict__ BT,
                                                      void* __restrict__ Cout,
                                                      int M, int N, int K) {
  __shared__ short As[128 * 32];
  __shared__ short Bs[128 * 32];
  const int t = threadIdx.x;
  const int lane = t & 63, w = t >> 6;
  const int c = lane & 15, g = lane >> 4;
  const int wm = w >> 1, wn = w & 1;
  const int mbase = blockIdx.y * 128, nbase = blockIdx.x * 128;
  const short* Ab = A + (size_t)mbase * K;
  const short* Bb = BT + (size_t)nbase * K;
  const int sr  = t >> 2;        // staging row 0..63
  const int sc2 = (t & 3) * 8;   // staging col chunk (8 bf16 = 16 B)
  f32x4 acc[4][4] = {};
  for (int kb2 = 0; kb2 < K; kb2 += 32) {
    glds16(Ab + (size_t)sr * K + kb2 + sc2,        As + t * 8);
    glds16(Ab + (size_t)(sr + 64) * K + kb2 + sc2, As + 2048 + t * 8);
    glds16(Bb + (size_t)sr * K + kb2 + sc2,        Bs + t * 8);
    glds16(Bb + (size_t)(sr + 64) * K + kb2 + sc2, Bs + 2048 + t * 8);
    __syncthreads();
    bf16x8 af[4], bfr[4];
    #pragma unroll
    for (int mi = 0; mi < 4; ++mi)
      af[mi] = *(const bf16x8*)&As[(wm * 64 + mi * 16 + c) * 32 + g * 8];
    #pragma unroll
    for (int ni = 0; ni < 4; ++ni)
      bfr[ni] = *(const bf16x8*)&Bs[(wn * 64 + ni * 16 + c) * 32 + g * 8];
    #pragma unroll
    for (int mi = 0; mi < 4; ++mi)
      #pragma unroll
      for (int ni = 0; ni < 4; ++ni)
        acc[mi][ni] = mfma16x16x32(af[mi], bfr[ni], acc[mi][ni]);
    __syncthreads();
  }
  #pragma unroll
  for (int mi = 0; mi < 4; ++mi) {
    const int row = mbase + wm * 64 + mi * 16 + g * 4;
    #pragma unroll
    for (int ni = 0; ni < 4; ++ni) {
      const int col = nbase + wn * 64 + ni * 16 + c;
      #pragma unroll
      for (int r = 0; r < 4; ++r) {
        if constexpr (OUTBF16)
          ((short*)Cout)[(size_t)(row + r) * N + col] = f2bf(acc[mi][ni][r]);
        else
          ((float*)Cout)[(size_t)(row + r) * N + col] = acc[mi][ni][r];
      }
    }
  }
}

// ---------------------------------------------------------------------------
// 5) RoPE on q,k: qkv bf16 [4096][3072] cols 0..2047 -> qb/kb [BH][N][64] bf16
//    q additionally scaled by 0.125 (exact pow2, folds softmax scale)
// ---------------------------------------------------------------------------
__global__ __launch_bounds__(256) void ropeqk_kernel(const short* __restrict__ qkv,
                                                     const float* __restrict__ cs,
                                                     short* __restrict__ qb,
                                                     short* __restrict__ kb) {
  int tid = blockIdx.x * 256 + threadIdx.x;  // 2097152 threads, 4 elems each
  int e   = tid * 4;
  int bn  = e >> 11;
  int col = e & 2047;
  int i3  = col >> 10;
  int h   = (col >> 6) & 15;
  int d   = col & 63;
  int n   = bn & (N_ - 1);
  int b   = bn >> 11;
  bf16x4 v = *(const bf16x4*)(qkv + (size_t)bn * 3072 + col);
  float4 t4 = *(const float4*)(cs + ((size_t)n * 32 + (d >> 1)) * 2); // c0,s0,c1,s1
  float x0 = bf2f(v[0]), x1 = bf2f(v[1]), x2 = bf2f(v[2]), x3 = bf2f(v[3]);
  float r0 = x0 * t4.x - x1 * t4.y;
  float r1 = x0 * t4.y + x1 * t4.x;
  float r2 = x2 * t4.z - x3 * t4.w;
  float r3 = x2 * t4.w + x3 * t4.z;
  float sc = (i3 == 0) ? 0.125f : 1.0f;
  bf16x4 ov;
  ov[0] = f2bf(r0 * sc); ov[1] = f2bf(r1 * sc);
  ov[2] = f2bf(r2 * sc); ov[3] = f2bf(r3 * sc);
  short* dst = (i3 == 0) ? qb : kb;
  *(bf16x4*)(dst + (((size_t)(b * H_ + h) * N_ + n) * DH_ + d)) = ov;
}

// ---------------------------------------------------------------------------
// 6) V transpose: qkv cols 2048..3071 -> vT [BH][64][N] bf16
// ---------------------------------------------------------------------------
__global__ __launch_bounds__(256) void transv_kernel(const short* __restrict__ qkv,
                                                     short* __restrict__ vT) {
  __shared__ unsigned short lds[64 * 65];
  const int t = threadIdx.x;
  const int ntile = blockIdx.x;  // 0..31
  const int bh = blockIdx.y;     // 0..31
  const int b = bh >> 4, h = bh & 15;
  #pragma unroll
  for (int pass = 0; pass < 2; ++pass) {
    int rloc = pass * 32 + (t >> 3);
    int dc = t & 7;
    const short* src = qkv + (size_t)(b * N_ + ntile * 64 + rloc) * 3072 + 2048 + h * 64 + dc * 8;
    bf16x8 v = *(const bf16x8*)src;
    #pragma unroll
    for (int j = 0; j < 8; ++j) lds[(dc * 8 + j) * 65 + rloc] = (unsigned short)v[j];
  }
  __syncthreads();
  const int dl = t >> 2, chunk = t & 3;
  bf16x8 o0, o1;
  #pragma unroll
  for (int j = 0; j < 8; ++j) {
    o0[j] = (short)lds[dl * 65 + chunk * 16 + j];
    o1[j] = (short)lds[dl * 65 + chunk * 16 + 8 + j];
  }
  short* dst = vT + ((size_t)bh * 64 + dl) * N_ + ntile * 64 + chunk * 16;
  *(bf16x8*)dst       = o0;
  *(bf16x8*)(dst + 8) = o1;
}

// ---------------------------------------------------------------------------
// 7) Flash attention, reg-staged double-buffered LDS (T14 async-split).
//    Block = 4 waves x 32 q-rows = 128 q-rows; KVBLK = 64.
//    Staging: plain global loads (linear, coalesced) -> regs at iteration
//    start; ds_write_b128 to the XOR-swizzled dest of the idle buffer after
//    compute; one __syncthreads per iteration. Storage relation:
//    LDS chunk q of row r holds global chunk q^(r&7)  (involution).
//    Swapped QK (S^T = mfma(K,Q)); PV via consistent k<->j slot remap so the
//    B-operand is the lane's own packed P registers (no shuffles).
// ---------------------------------------------------------------------------
__global__ __launch_bounds__(256) void attn_kernel(const short* __restrict__ qb,
                                                   const short* __restrict__ kb,
                                                   const short* __restrict__ vT,
                                                   short* __restrict__ attn_out) {
  __shared__ short Kt[2][4096];   // 8 KB per buf: [row 0..63][chunk 0..7][8]
  __shared__ short Vt[2][4096];
  const int t = threadIdx.x;
  const int lane = t & 63, w = t >> 6;
  const int c = lane & 15, g = lane >> 4;
  const int bh = blockIdx.y;
  const int qbase = blockIdx.x * 128 + w * 32;
  const short* kbase = kb + (size_t)bh * N_ * DH_;
  const short* vbase = vT + (size_t)bh * DH_ * N_;

  // staging map (per thread, 2 chunks per array): ch = j*256+t
  const int s_row0 = t >> 3,          s_p0 = t & 7;
  const int s_row1 = (256 + t) >> 3,  s_p1 = t & 7;   // rows 32..63
  const int s_dst0 = s_row0 * 64 + ((s_p0 ^ (s_row0 & 7)) << 3);
  const int s_dst1 = s_row1 * 64 + ((s_p1 ^ (s_row1 & 7)) << 3);

  // Q fragments held in registers for the whole kv loop; q pre-scaled 1/8
  bf16x8 qlo[2], qhi[2];
  #pragma unroll
  for (int qf = 0; qf < 2; ++qf) {
    const short* qp = qb + ((size_t)bh * N_ + qbase + qf * 16 + c) * DH_;
    qlo[qf] = *(const bf16x8*)(qp + g * 8);
    qhi[qf] = *(const bf16x8*)(qp + 32 + g * 8);
  }

  float M[2] = {-INFINITY, -INFINITY};
  float L[2] = {0.f, 0.f};
  f32x4 o[4][2] = {};
  bf16x8 kr0, kr1, vr0, vr1;

  // prologue: load tile 0 -> regs, write buf 0, barrier
  kr0 = *(const bf16x8*)(kbase + (size_t)s_row0 * DH_ + s_p0 * 8);
  kr1 = *(const bf16x8*)(kbase + (size_t)s_row1 * DH_ + s_p1 * 8);
  vr0 = *(const bf16x8*)(vbase + (size_t)s_row0 * N_ + s_p0 * 8);
  vr1 = *(const bf16x8*)(vbase + (size_t)s_row1 * N_ + s_p1 * 8);
  *(bf16x8*)(&Kt[0][s_dst0]) = kr0;
  *(bf16x8*)(&Kt[0][s_dst1]) = kr1;
  *(bf16x8*)(&Vt[0][s_dst0]) = vr0;
  *(bf16x8*)(&Vt[0][s_dst1]) = vr1;
  __syncthreads();

  for (int it = 0; it < 32; ++it) {
    const int cur = it & 1;
    const int pf_valid = (it + 1 < 32);
    if (pf_valid) {  // issue next-tile loads BEFORE compute (overlap)
      const int kv = (it + 1) * 64;
      kr0 = *(const bf16x8*)(kbase + (size_t)(kv + s_row0) * DH_ + s_p0 * 8);
      kr1 = *(const bf16x8*)(kbase + (size_t)(kv + s_row1) * DH_ + s_p1 * 8);
      vr0 = *(const bf16x8*)(vbase + (size_t)s_row0 * N_ + kv + s_p0 * 8);
      vr1 = *(const bf16x8*)(vbase + (size_t)s_row1 * N_ + kv + s_p1 * 8);
    }
    // --- QK^T: s lane holds S[q=qf*16+c][j=it*64+jt*16+g*4+r] ---
    f32x4 s[4][2] = {};
    #pragma unroll
    for (int jt = 0; jt < 4; ++jt) {
      const int r_ = jt * 16 + c;
      const short* kt = &Kt[cur][r_ * 64];
      bf16x8 k0 = *(const bf16x8*)(kt + ((g ^ (r_ & 7)) << 3));
      bf16x8 k1 = *(const bf16x8*)(kt + (((g + 4) ^ (r_ & 7)) << 3));
      #pragma unroll
      for (int qf = 0; qf < 2; ++qf) {
        s[jt][qf] = mfma16x16x32(k0, qlo[qf], s[jt][qf]);
        s[jt][qf] = mfma16x16x32(k1, qhi[qf], s[jt][qf]);
      }
    }
    // --- online softmax + P pack ---
    bf16x8 pf[2][2];
    #pragma unroll
    for (int qf = 0; qf < 2; ++qf) {
      float mx = -INFINITY;
      #pragma unroll
      for (int jt = 0; jt < 4; ++jt)
        #pragma unroll
        for (int r = 0; r < 4; ++r) mx = fmaxf(mx, s[jt][qf][r]);
      mx = fmaxf(mx, __shfl_xor(mx, 16));
      mx = fmaxf(mx, __shfl_xor(mx, 32));
      const float mnew = fmaxf(M[qf], mx);
      const float corr = __expf(M[qf] - mnew);  // exp(-inf)=0 first tile
      float rs = 0.f;
      #pragma unroll
      for (int jt = 0; jt < 4; ++jt)
        #pragma unroll
        for (int r = 0; r < 4; ++r) {
          s[jt][qf][r] = __expf(s[jt][qf][r] - mnew);
          rs += s[jt][qf][r];
        }
      rs += __shfl_xor(rs, 16);
      rs += __shfl_xor(rs, 32);
      L[qf] = L[qf] * corr + rs;
      M[qf] = mnew;
      #pragma unroll
      for (int dt = 0; dt < 4; ++dt) o[dt][qf] *= corr;
      bf16x8 p0, p1;
      #pragma unroll
      for (int r = 0; r < 4; ++r) {
        p0[r]     = f2bf(s[0][qf][r]);
        p0[4 + r] = f2bf(s[1][qf][r]);
        p1[r]     = f2bf(s[2][qf][r]);
        p1[4 + r] = f2bf(s[3][qf][r]);
      }
      pf[qf][0] = p0;
      pf[qf][1] = p1;
    }
    // --- PV: A = V^T rows d, slot map j = kf*32 + (s<4 ? g*4+s : 16+g*4+s-4)
    #pragma unroll
    for (int dt = 0; dt < 4; ++dt) {
      const int d = dt * 16 + c;
      const short* vt = &Vt[cur][d * 64];
      const int dx = d & 7;
      #pragma unroll
      for (int kf = 0; kf < 2; ++kf) {
        const int e0 = kf * 32 + g * 4;
        const int e1 = e0 + 16;
        bf16x4 a0 = *(const bf16x4*)(vt + ((((e0 >> 3) ^ dx) << 3) | (e0 & 7)));
        bf16x4 a1 = *(const bf16x4*)(vt + ((((e1 >> 3) ^ dx) << 3) | (e1 & 7)));
        bf16x8 vf = __builtin_shufflevector(a0, a1, 0, 1, 2, 3, 4, 5, 6, 7);
        o[dt][0] = mfma16x16x32(vf, pf[0][kf], o[dt][0]);
        o[dt][1] = mfma16x16x32(vf, pf[1][kf], o[dt][1]);
      }
    }
    // --- write-late: store prefetched regs into the idle buffer ---
    if (pf_valid) {
      *(bf16x8*)(&Kt[cur ^ 1][s_dst0]) = kr0;
      *(bf16x8*)(&Kt[cur ^ 1][s_dst1]) = kr1;
      *(bf16x8*)(&Vt[cur ^ 1][s_dst0]) = vr0;
      *(bf16x8*)(&Vt[cur ^ 1][s_dst1]) = vr1;
    }
    __syncthreads();
  }

  const int b = bh >> 4, h = bh & 15;
  #pragma unroll
  for (int qf = 0; qf < 2; ++qf) {
    const float inv = 1.0f / L[qf];
    short* op = attn_out + ((size_t)b * N_ + qbase + qf * 16 + c) * (H_ * DH_) + h * DH_;
    #pragma unroll
    for (int dt = 0; dt < 4; ++dt) {
      bf16x4 ov;
      #pragma unroll
      for (int r = 0; r < 4; ++r) ov[r] = f2bf(o[dt][qf][r] * inv);
      *(bf16x4*)(op + dt * 16 + g * 4) = ov;
    }
  }
}

// ---------------------------------------------------------------------------
extern "C" void kernel_launch(void* const* d_in, const int* in_sizes, int n_in,
                              void* d_out, int out_size, void* d_ws, size_t ws_size,
                              hipStream_t stream) {
  const float* x    = (const float*)d_in[0];
  const float* Wqkv = (const float*)d_in[1];
  const float* Wout = (const float*)d_in[2];
  char* ws = (char*)d_ws;
  // workspace layout (MiB offsets)
  short* xb    = (short*)(ws);                        // 8 MiB  [4096][1024]
  short* WqkvT = (short*)(ws + ((size_t)8 << 20));    // 6 MiB  [3072][1024]
  short* WoutT = (short*)(ws + ((size_t)14 << 20));   // 2 MiB  [1024][1024]
  short* qkv   = (short*)(ws + ((size_t)16 << 20));   // 24 MiB [4096][3072]
  short* qb    = (short*)(ws + ((size_t)40 << 20));   // 8 MiB  [32][2048][64]
  short* kb    = (short*)(ws + ((size_t)48 << 20));   // 8 MiB
  short* vT    = (short*)(ws + ((size_t)56 << 20));   // 8 MiB  [32][64][2048]
  short* attn  = (short*)(ws + ((size_t)64 << 20));   // 8 MiB  [4096][1024]
  float* cs    = (float*)(ws + ((size_t)72 << 20));   // 0.5 MiB [2048][32][2]

  cs_kernel<<<dim3(256), 256, 0, stream>>>(cs);
  conv_kernel<<<dim3(2048), 256, 0, stream>>>(x, xb);                       // x -> bf16
  transw_kernel<<<dim3(48, 16), 256, 0, stream>>>(Wqkv, WqkvT, 1024, 3072); // Wqkv^T
  transw_kernel<<<dim3(16, 16), 256, 0, stream>>>(Wout, WoutT, 1024, 1024); // Wout^T
  gemm_bt_kernel<true><<<dim3(24, 32), 256, 0, stream>>>(xb, WqkvT, (void*)qkv, 4096, 3072, 1024);
  ropeqk_kernel<<<dim3(8192), 256, 0, stream>>>(qkv, cs, qb, kb);
  transv_kernel<<<dim3(32, 32), 256, 0, stream>>>(qkv, vT);
  attn_kernel<<<dim3(16, 32), 256, 0, stream>>>(qb, kb, vT, attn);
  gemm_bt_kernel<false><<<dim3(8, 32), 256, 0, stream>>>(attn, WoutT, d_out, 4096, 1024, 1024);
}